// Round 8
// baseline (651.913 us; speedup 1.0000x reference)
//
#include <hip/hip_runtime.h>
#include <hip/hip_bf16.h>
#include <math.h>

#define B_   2048
#define N_   38
#define E_   4
#define DIN_ 9
#define H0_  256
#define H1_  256
#define L0_  512
#define M_   (B_ * N_)

typedef short bf16x8 __attribute__((ext_vector_type(8)));
typedef float f32x4 __attribute__((ext_vector_type(4)));

// ---------- bf16 helpers ----------
struct __align__(8) bf4 { __hip_bfloat16 x, y, z, w; };

__device__ __forceinline__ float b2f(unsigned short u) {
  return __uint_as_float((unsigned)u << 16);
}
__device__ __forceinline__ unsigned short f2b(float f) {
  __hip_bfloat16 h = __float2bfloat16(f);
  return *(unsigned short*)&h;
}
__device__ __forceinline__ void st4v(__hip_bfloat16* p, float4 v) {
  bf4 o;
  o.x = __float2bfloat16(v.x); o.y = __float2bfloat16(v.y);
  o.z = __float2bfloat16(v.z); o.w = __float2bfloat16(v.w);
  *(bf4*)p = o;
}

static __device__ __forceinline__ float selc(const float4 v, int j) {
  return (j == 0) ? v.x : ((j == 1) ? v.y : ((j == 2) ? v.z : v.w));
}

__device__ __forceinline__ void fma_tile12(const float* __restrict__ zr, float4 w,
                                           float (&acc)[4][12]) {
#pragma unroll
  for (int l4 = 0; l4 < 3; ++l4) {
    float4 zv = *(const float4*)&zr[l4 * 4];
#pragma unroll
    for (int j = 0; j < 4; ++j) {
      float wj = selc(w, j);
      acc[j][l4 * 4 + 0] = fmaf(zv.x, wj, acc[j][l4 * 4 + 0]);
      acc[j][l4 * 4 + 1] = fmaf(zv.y, wj, acc[j][l4 * 4 + 1]);
      acc[j][l4 * 4 + 2] = fmaf(zv.z, wj, acc[j][l4 * 4 + 2]);
      acc[j][l4 * 4 + 3] = fmaf(zv.w, wj, acc[j][l4 * 4 + 3]);
    }
  }
}

// wt0 fp32 [45][256]
__global__ void k_build_w0(const float* __restrict__ Ws, const float* __restrict__ We,
                           float* __restrict__ WT) {
  int i = blockIdx.x * 256 + threadIdx.x;
  if (i >= 45 * 256) return;
  int r = i / 256, c = i % 256;
  float v;
  if (r < 9) v = Ws[c * 9 + r];
  else { int rr = r - 9; int e = rr / 9, f = rr % 9; v = We[(c * 4 + e) * 9 + f]; }
  WT[i] = v;
}

// Wbig bf16 [1280][256]
__global__ void k_build_wbig(const float* __restrict__ Ws, const float* __restrict__ We,
                             unsigned short* __restrict__ WT) {
  int i = blockIdx.x * 256 + threadIdx.x;
  if (i >= 1280 * 256) return;
  int j = i / 256, f = i % 256;
  float v;
  if (j < 256) v = Ws[j * 256 + f];
  else { int jj = j - 256; int e = jj >> 8, c = jj & 255; v = We[(c * 4 + e) * 256 + f]; }
  WT[i] = f2b(v);
}

// Wl bf16 [512][256]
__global__ void k_build_wl(const float* __restrict__ W, unsigned short* __restrict__ WT) {
  int i = blockIdx.x * 256 + threadIdx.x;
  if (i >= 512 * 256) return;
  WT[i] = f2b(W[i]);
}

// Wfb bf16 [32][512]
__global__ void k_build_wf(const float* __restrict__ W, unsigned short* __restrict__ WT) {
  int i = blockIdx.x * 256 + threadIdx.x;
  if (i >= 32 * 512) return;
  int r = i / 512, k = i % 512;
  WT[i] = f2b(r < 18 ? W[r * 512 + k] : 0.f);
}

// partials reduce: part[nblk][76] -> st (76 entries interleaved sum/sq per n)
__global__ __launch_bounds__(256) void k_gred(const float* __restrict__ part, int nblk,
                                              float* __restrict__ st) {
  const int j = blockIdx.x, tid = threadIdx.x;
  float s = 0.f;
  for (int i = tid; i < nblk; i += 256) s += part[(size_t)i * 76 + j];
#pragma unroll
  for (int off = 32; off; off >>= 1) s += __shfl_down(s, off);
  __shared__ float r[4];
  if ((tid & 63) == 0) r[tid >> 6] = s;
  __syncthreads();
  if (tid == 0) {
    float tot = r[0] + r[1] + r[2] + r[3];
    if (j < 38) st[j * 2] = tot;
    else st[(j - 38) * 2 + 1] = tot;
  }
}

// ---------------- gconv layer 0 (K=45), fp32 VALU, output bf16 + stats partials ----------------
__global__ __launch_bounds__(256) void k_gconv0(
    const float* __restrict__ adj, const float* __restrict__ x,
    const float* __restrict__ WT, const float* __restrict__ bs,
    const float* __restrict__ be, __hip_bfloat16* __restrict__ g,
    float* __restrict__ part) {
  __shared__ __align__(16) float adjF[E_ * N_ * N_];
  __shared__ __align__(16) float xc[45 * 48];
  __shared__ __align__(16) float arow[E_ * 48];
  __shared__ float lsum[38], lsq[38];
  const int b = blockIdx.x, tid = threadIdx.x;
  if (tid < 38) { lsum[tid] = 0.f; lsq[tid] = 0.f; }
  const size_t abase = (size_t)b * (E_ * N_ * N_);
  for (int i = tid; i < E_ * N_ * N_; i += 256) adjF[i] = adj[abase + i];
  for (int i = tid; i < N_ * DIN_; i += 256) {
    int n = i / DIN_;
    float v = x[(size_t)b * (N_ * DIN_) + i];
    xc[(i % DIN_) * 48 + n] = (n & 1) ? v : 0.f;   // MASK zeroes even rows
  }
  __syncthreads();
  for (int i = tid; i < E_ * N_; i += 256) {
    int e = i / N_, m = i % N_;
    const float* ar = &adjF[(e * N_ + m) * N_];
    float s = 0.f;
    for (int n = 0; n < N_; ++n) s += ar[n];
    arow[e * 48 + m] = s;
  }
  for (int i = tid; i < 36 * N_; i += 256) {
    int m = i % N_, ef = i / N_;
    int e = ef / 9, f = ef % 9;
    const float* ar = &adjF[(e * N_ + m) * N_];
    float s = 0.f;
    for (int n = 0; n < N_; ++n) s += ar[n] * xc[f * 48 + n];
    xc[(9 + ef) * 48 + m] = s;
  }
  __syncthreads();
  const int cg = tid & 63, mg = tid >> 6;
  const int c0 = cg * 4, mb = mg * 12;
  float acc[4][12];
#pragma unroll
  for (int j = 0; j < 4; ++j) {
    float bsv = bs[c0 + j];
    float b0 = be[(c0 + j) * 4 + 0], b1 = be[(c0 + j) * 4 + 1];
    float b2 = be[(c0 + j) * 4 + 2], b3 = be[(c0 + j) * 4 + 3];
#pragma unroll
    for (int l = 0; l < 12; ++l) {
      int m = mb + l;
      acc[j][l] = bsv + arow[0 * 48 + m] * b0 + arow[1 * 48 + m] * b1 +
                  arow[2 * 48 + m] * b2 + arow[3 * 48 + m] * b3;
    }
  }
  for (int k = 0; k < 45; ++k) {
    float4 w = *(const float4*)&WT[k * 256 + c0];
    fma_tile12(&xc[k * 48 + mb], w, acc);
  }
#pragma unroll
  for (int l = 0; l < 12; ++l) {
    int m = mb + l;
    if (m < N_) {
      float4 o; o.x = acc[0][l]; o.y = acc[1][l]; o.z = acc[2][l]; o.w = acc[3][l];
      st4v(&g[((size_t)b * N_ + m) * H0_ + c0], o);
      float s = o.x + o.y + o.z + o.w;
      float q = o.x * o.x + o.y * o.y + o.z * o.z + o.w * o.w;
      atomicAdd(&lsum[m], s);
      atomicAdd(&lsq[m], q);
    }
  }
  __syncthreads();
  if (tid < 38) {
    part[(size_t)b * 76 + tid] = lsum[tid];
    part[(size_t)b * 76 + 38 + tid] = lsq[tid];
  }
}

// ---------------- k_gemm: 128x256 MFMA GEMM with fused BN+ReLU on A ----------------
// A raw bf16 [rows][256]; BN coeffs from stIn (per n=row%38). Optional bias + stats partials.
template <bool BIAS, bool STATS>
__global__ __launch_bounds__(512) void k_gemm(
    const unsigned short* __restrict__ A0, const unsigned short* __restrict__ Bw,
    const float* __restrict__ bias, const float* __restrict__ stIn,
    const float* __restrict__ gam, const float* __restrict__ bet, float cnt,
    unsigned short* __restrict__ Cout, int Cstride, float* __restrict__ part) {
  __shared__ __align__(16) unsigned short lA[128 * 32];
  __shared__ __align__(16) unsigned short lB[256 * 32];
  __shared__ float lbias[256];
  __shared__ float lsum[38], lsq[38];
  const int t = threadIdx.x;
  const int tileM = blockIdx.x, n_base = blockIdx.y * 256;
  if (BIAS && t < 256) lbias[t] = bias[n_base + t];
  if (STATS && t < 38) { lsum[t] = 0.f; lsq[t] = 0.f; }
  const int w = t >> 6, L = t & 63;
  const int wr = w >> 2, wc = w & 3;
  const int lrow = L & 15, quad = L >> 4;
  const int srow = t >> 2, sseg = (t & 3) * 8;
  // per-thread BN coeffs for the A row it stages
  const int nA = (tileM * 128 + srow) % 38;
  float aC, bC;
  {
    float mu = stIn[nA * 2] / cnt;
    float var = stIn[nA * 2 + 1] / cnt - mu * mu;
    aC = rsqrtf(var + 1e-5f) * gam[nA];
    bC = bet[nA] - mu * aC;
  }
  const unsigned short* aRow = A0 + (size_t)(tileM * 128 + srow) * 256 + sseg;
  f32x4 acc[4][4];
#pragma unroll
  for (int mt = 0; mt < 4; ++mt)
#pragma unroll
    for (int nt = 0; nt < 4; ++nt) acc[mt][nt] = (f32x4){0.f, 0.f, 0.f, 0.f};

  uint4 u = *(const uint4*)aRow;
  for (int ki = 0; ki < 8; ++ki) {
    uint4 un;
    if (ki < 7) un = *(const uint4*)(aRow + (ki + 1) * 32);
    // BN+ReLU + pack -> LDS
    {
      uint4 o;
      unsigned* up = (unsigned*)&u;
      unsigned* op = (unsigned*)&o;
#pragma unroll
      for (int j = 0; j < 4; ++j) {
        float lo = fmaxf(fmaf(b2f((unsigned short)(up[j] & 0xffff)), aC, bC), 0.f);
        float hi = fmaxf(fmaf(b2f((unsigned short)(up[j] >> 16)), aC, bC), 0.f);
        op[j] = (unsigned)f2b(lo) | ((unsigned)f2b(hi) << 16);
      }
      *(uint4*)&lA[srow * 32 + sseg] = o;
    }
#pragma unroll
    for (int r = 0; r < 2; ++r) {
      const unsigned short* gp = Bw + (size_t)(n_base + r * 128 + srow) * 256 + ki * 32 + sseg;
      __builtin_amdgcn_global_load_lds(
          (const __attribute__((address_space(1))) void*)gp,
          (__attribute__((address_space(3))) void*)(lB + r * 4096 + w * 512), 16, 0, 0);
    }
    __syncthreads();
    bf16x8 af[4], bfr[4];
#pragma unroll
    for (int mt = 0; mt < 4; ++mt)
      af[mt] = *(const bf16x8*)&lA[(wr * 64 + mt * 16 + lrow) * 32 + quad * 8];
#pragma unroll
    for (int nt = 0; nt < 4; ++nt)
      bfr[nt] = *(const bf16x8*)&lB[(wc * 64 + nt * 16 + lrow) * 32 + quad * 8];
#pragma unroll
    for (int mt = 0; mt < 4; ++mt)
#pragma unroll
      for (int nt = 0; nt < 4; ++nt)
        acc[mt][nt] = __builtin_amdgcn_mfma_f32_16x16x32_bf16(af[mt], bfr[nt], acc[mt][nt], 0, 0, 0);
    __syncthreads();
    u = un;
  }
#pragma unroll
  for (int mt = 0; mt < 4; ++mt) {
#pragma unroll
    for (int reg = 0; reg < 4; ++reg) {
      const size_t row = (size_t)tileM * 128 + wr * 64 + mt * 16 + quad * 4 + reg;
      float sv = 0.f, qv = 0.f;
#pragma unroll
      for (int nt = 0; nt < 4; ++nt) {
        const int lcol = wc * 64 + nt * 16 + lrow;
        float v = acc[mt][nt][reg];
        if (BIAS) v += lbias[lcol];
        Cout[row * Cstride + n_base + lcol] = f2b(v);
        sv += v;
        qv += v * v;
      }
      if (STATS) {
        int n = (int)(row % 38);
        atomicAdd(&lsum[n], sv);
        atomicAdd(&lsq[n], qv);
      }
    }
  }
  if (STATS) {
    __syncthreads();
    const int blk = blockIdx.y * gridDim.x + blockIdx.x;
    if (t < 38) {
      part[(size_t)blk * 76 + t] = lsum[t];
      part[(size_t)blk * 76 + 38 + t] = lsq[t];
    }
  }
}

// ---------------- k_hr: per-b contraction hr = adj_e x Y_e, + hs + bias + arow.be + stats ----------------
__global__ __launch_bounds__(256) void k_hr(
    const float* __restrict__ adj, const unsigned short* __restrict__ Y,
    const float* __restrict__ bs, const float* __restrict__ be,
    unsigned short* __restrict__ h2, int b_base, float* __restrict__ part) {
  __shared__ __align__(16) unsigned short adjE[4 * 48 * 64];
  __shared__ __align__(16) unsigned short Ybt[256 * 72];
  __shared__ float arowS[4 * 48];
  __shared__ float lsum[38], lsq[38];
  const int t = threadIdx.x;
  const int bl = blockIdx.x, b = b_base + bl;
  if (t < 38) { lsum[t] = 0.f; lsq[t] = 0.f; }
  for (int i = t; i < 4 * 48 * 64 / 8; i += 256) ((uint4*)adjE)[i] = make_uint4(0, 0, 0, 0);
#pragma unroll
  for (int n = 38; n < 64; ++n) Ybt[t * 72 + n] = 0;
  __syncthreads();
  for (int i = t; i < 4 * 38 * 38; i += 256) {
    int e = i / 1444, r = i % 1444, m = r / 38, n = r % 38;
    adjE[(e * 48 + m) * 64 + n] = f2b(adj[(size_t)b * 5776 + i]);
  }
  __syncthreads();
  if (t < 152) {
    int e = t / 38, m = t % 38;
    float s = 0.f;
    for (int n = 0; n < 38; ++n) s += b2f(adjE[(e * 48 + m) * 64 + n]);
    arowS[e * 48 + m] = s;
  }
  const int w = t >> 6, L = t & 63;
  const int lrow = L & 15, quad = L >> 4;
  f32x4 acc[3][4];
#pragma unroll
  for (int mt = 0; mt < 3; ++mt)
#pragma unroll
    for (int nt = 0; nt < 4; ++nt) acc[mt][nt] = (f32x4){0.f, 0.f, 0.f, 0.f};
#pragma unroll 1
  for (int e = 0; e < 4; ++e) {
    __syncthreads();
    {
      const unsigned short* yp = Y + (size_t)bl * 38 * 1280 + 256 + e * 256 + t;
#pragma unroll
      for (int n = 0; n < 38; ++n) Ybt[t * 72 + n] = yp[(size_t)n * 1280];
    }
    __syncthreads();
#pragma unroll
    for (int kk = 0; kk < 2; ++kk) {
      bf16x8 bb[4];
#pragma unroll
      for (int nt = 0; nt < 4; ++nt)
        bb[nt] = *(const bf16x8*)&Ybt[(w * 64 + nt * 16 + lrow) * 72 + kk * 32 + quad * 8];
#pragma unroll
      for (int mt = 0; mt < 3; ++mt) {
        bf16x8 aa = *(const bf16x8*)&adjE[(e * 48 + mt * 16 + lrow) * 64 + kk * 32 + quad * 8];
#pragma unroll
        for (int nt = 0; nt < 4; ++nt)
          acc[mt][nt] = __builtin_amdgcn_mfma_f32_16x16x32_bf16(aa, bb[nt], acc[mt][nt], 0, 0, 0);
      }
    }
  }
#pragma unroll
  for (int mt = 0; mt < 3; ++mt) {
#pragma unroll
    for (int reg = 0; reg < 4; ++reg) {
      const int m = mt * 16 + quad * 4 + reg;
      if (m < N_) {
        float a0 = arowS[0 * 48 + m], a1 = arowS[1 * 48 + m];
        float a2 = arowS[2 * 48 + m], a3 = arowS[3 * 48 + m];
        float sv = 0.f, qv = 0.f;
#pragma unroll
        for (int nt = 0; nt < 4; ++nt) {
          const int col = w * 64 + nt * 16 + lrow;
          float hs = b2f(Y[(size_t)(bl * 38 + m) * 1280 + col]);
          float4 bev = *(const float4*)&be[col * 4];
          float v = acc[mt][nt][reg] + hs + bs[col] +
                    a0 * bev.x + a1 * bev.y + a2 * bev.z + a3 * bev.w;
          h2[((size_t)b * N_ + m) * 256 + col] = f2b(v);
          sv += v;
          qv += v * v;
        }
        atomicAdd(&lsum[m], sv);
        atomicAdd(&lsq[m], qv);
      }
    }
  }
  __syncthreads();
  if (t < 38) {
    part[(size_t)b * 76 + t] = lsum[t];
    part[(size_t)b * 76 + 38 + t] = lsq[t];
  }
}

// ---------------- final: MFMA 512->18 + coupling + logdet, BN2+ReLU fused ----------------
__global__ __launch_bounds__(256) void k_final(
    const unsigned short* __restrict__ g2, const float* __restrict__ x,
    const unsigned short* __restrict__ Wfb, const float* __restrict__ fb,
    const float* __restrict__ st, const float* __restrict__ gam,
    const float* __restrict__ bet, float* __restrict__ out) {
  __shared__ __align__(16) unsigned short hA[48 * 520];
  __shared__ float lgS[48 * 20];
  __shared__ float aS[N_], bS[N_], fbS[20], red[4];
  const int b = blockIdx.x, tid = threadIdx.x;
  if (tid < N_) {
    const float cnt = 2048.f * 512.f;
    float mu = st[tid * 2] / cnt;
    float var = st[tid * 2 + 1] / cnt - mu * mu;
    float a = rsqrtf(var + 1e-5f) * gam[tid];
    aS[tid] = a;
    bS[tid] = bet[tid] - mu * a;
  }
  if (tid >= 64 && tid < 82) fbS[tid - 64] = fb[tid - 64];
  __syncthreads();
  for (int i = tid; i < N_ * 64; i += 256) {
    int n = i >> 6, seg = (i & 63) * 8;
    uint4 u = *(const uint4*)&g2[((size_t)b * N_ + n) * 512 + seg];
    float a = aS[n], bb = bS[n];
    float v[8];
    v[0] = b2f((unsigned short)(u.x & 0xffff)); v[1] = b2f((unsigned short)(u.x >> 16));
    v[2] = b2f((unsigned short)(u.y & 0xffff)); v[3] = b2f((unsigned short)(u.y >> 16));
    v[4] = b2f((unsigned short)(u.z & 0xffff)); v[5] = b2f((unsigned short)(u.z >> 16));
    v[6] = b2f((unsigned short)(u.w & 0xffff)); v[7] = b2f((unsigned short)(u.w >> 16));
#pragma unroll
    for (int j = 0; j < 8; ++j) v[j] = fmaxf(fmaf(v[j], a, bb), 0.f);
    uint4 o;
    o.x = (unsigned)f2b(v[0]) | ((unsigned)f2b(v[1]) << 16);
    o.y = (unsigned)f2b(v[2]) | ((unsigned)f2b(v[3]) << 16);
    o.z = (unsigned)f2b(v[4]) | ((unsigned)f2b(v[5]) << 16);
    o.w = (unsigned)f2b(v[6]) | ((unsigned)f2b(v[7]) << 16);
    *(uint4*)&hA[n * 520 + seg] = o;
  }
  for (int i = tid; i < 10 * 64; i += 256) {
    int n = 38 + (i >> 6), seg = (i & 63) * 8;
    *(uint4*)&hA[n * 520 + seg] = make_uint4(0, 0, 0, 0);
  }
  __syncthreads();
  const int w = tid >> 6, L = tid & 63;
  const int lrow = L & 15, quad = L >> 4;
  if (w < 3) {
    f32x4 acc0 = (f32x4){0.f, 0.f, 0.f, 0.f}, acc1 = (f32x4){0.f, 0.f, 0.f, 0.f};
#pragma unroll
    for (int ki = 0; ki < 16; ++ki) {
      bf16x8 af = *(const bf16x8*)&hA[(w * 16 + lrow) * 520 + ki * 32 + quad * 8];
      bf16x8 b0 = *(const bf16x8*)&Wfb[(size_t)lrow * 512 + ki * 32 + quad * 8];
      bf16x8 b1 = *(const bf16x8*)&Wfb[(size_t)(16 + lrow) * 512 + ki * 32 + quad * 8];
      acc0 = __builtin_amdgcn_mfma_f32_16x16x32_bf16(af, b0, acc0, 0, 0, 0);
      acc1 = __builtin_amdgcn_mfma_f32_16x16x32_bf16(af, b1, acc1, 0, 0, 0);
    }
#pragma unroll
    for (int reg = 0; reg < 4; ++reg) {
      int m = w * 16 + quad * 4 + reg;
      if (m < N_) {
        lgS[m * 20 + lrow] = acc0[reg] + fbS[lrow];
        if (lrow < 2) lgS[m * 20 + 16 + lrow] = acc1[reg] + fbS[16 + lrow];
      }
    }
  }
  __syncthreads();
  float ls = 0.f;
  for (int ii = tid; ii < 342; ii += 256) {
    int mm = ii / 9, d = ii % 9;
    float sl = lgS[mm * 20 + d];
    float tv = lgS[mm * 20 + 9 + d];
    float xv = x[((size_t)b * N_ + mm) * 9 + d];
    float sg = 1.f / (1.f + expf(-sl));
    float o = (mm & 1) ? xv : (xv + tv) * sg;
    out[((size_t)b * N_ + mm) * 9 + d] = o;
    ls += (sl >= 0.f) ? -log1pf(expf(-sl)) : (sl - log1pf(expf(sl)));
  }
#pragma unroll
  for (int off = 32; off; off >>= 1) ls += __shfl_down(ls, off);
  if (L == 0) red[w] = ls;
  __syncthreads();
  if (tid == 0) out[(size_t)B_ * 342 + b] = red[0] + red[1] + red[2] + red[3];
}

extern "C" void kernel_launch(void* const* d_in, const int* in_sizes, int n_in,
                              void* d_out, int out_size, void* d_ws, size_t ws_size,
                              hipStream_t stream) {
  (void)in_sizes; (void)n_in; (void)out_size; (void)ws_size;
  const float* adj  = (const float*)d_in[0];
  const float* x    = (const float*)d_in[1];
  const float* cWs0 = (const float*)d_in[2];
  const float* cbs0 = (const float*)d_in[3];
  const float* cWe0 = (const float*)d_in[4];
  const float* cbe0 = (const float*)d_in[5];
  const float* cg0  = (const float*)d_in[6];
  const float* cb0  = (const float*)d_in[7];
  const float* cWs1 = (const float*)d_in[8];
  const float* cbs1 = (const float*)d_in[9];
  const float* cWe1 = (const float*)d_in[10];
  const float* cbe1 = (const float*)d_in[11];
  const float* cg1  = (const float*)d_in[12];
  const float* cb1  = (const float*)d_in[13];
  const float* lW0  = (const float*)d_in[14];
  const float* lb0  = (const float*)d_in[15];
  const float* lg0  = (const float*)d_in[16];
  const float* lbb0 = (const float*)d_in[17];
  const float* fW   = (const float*)d_in[18];
  const float* fb   = (const float*)d_in[19];
  float* out = (float*)d_out;

  // ---- workspace layout ----
  char* p = (char*)d_ws;
  float* stats = (float*)p;                     p += 1024;
  float* wt0   = (float*)p;                     p += 45 * 256 * 4;
  unsigned short* Wfb  = (unsigned short*)p;    p += 32 * 512 * 2;
  unsigned short* Wbig = (unsigned short*)p;    p += 1280 * 256 * 2;
  unsigned short* Wl   = (unsigned short*)p;    p += 512 * 256 * 2;
  float* part0 = (float*)p;                     p += 2048 * 76 * 4;
  float* part1 = (float*)p;                     p += 2048 * 76 * 4;
  float* part2 = (float*)p;                     p += 1216 * 76 * 4;
  unsigned short* g0   = (unsigned short*)p;    p += (size_t)M_ * 256 * 2;
  unsigned short* h2   = (unsigned short*)p;    p += (size_t)M_ * 256 * 2;
  unsigned short* big  = (unsigned short*)p;    // Y-half (99.6MB) then g2 (79.7MB)
  unsigned short* Ybuf = big;
  unsigned short* g2   = big;

  float* st0 = stats;
  float* st1 = stats + 76;
  float* st2 = stats + 152;

  k_build_w0<<<45, 256, 0, stream>>>(cWs0, cWe0, wt0);
  k_build_wbig<<<1280, 256, 0, stream>>>(cWs1, cWe1, Wbig);
  k_build_wl<<<512, 256, 0, stream>>>(lW0, Wl);
  k_build_wf<<<64, 256, 0, stream>>>(fW, Wfb);

  // layer 0 (writes g0 raw + stats partials)
  k_gconv0<<<2048, 256, 0, stream>>>(adj, x, wt0, cbs0, cbe0, (__hip_bfloat16*)g0, part0);
  k_gred<<<76, 256, 0, stream>>>(part0, 2048, st0);

  // layer 1: Y = BN0ReLU(g0) * Wbig^T, then per-b adj contraction; 2 halves
  for (int hh = 0; hh < 2; ++hh) {
    k_gemm<false, false><<<dim3(304, 5), 512, 0, stream>>>(
        g0 + (size_t)hh * (M_ / 2) * 256, Wbig, (const float*)nullptr,
        st0, cg0, cb0, 2048.f * 256.f, Ybuf, 1280, (float*)nullptr);
    k_hr<<<1024, 256, 0, stream>>>(adj, Ybuf, cbs1, cbe1, h2, hh * 1024, part1);
  }
  k_gred<<<76, 256, 0, stream>>>(part1, 2048, st1);

  // layer 2: g2 = BN1ReLU(h2) * Wl^T + lb0  (+ stats partials)
  k_gemm<true, true><<<dim3(608, 2), 512, 0, stream>>>(
      h2, Wl, lb0, st1, cg1, cb1, 2048.f * 256.f, g2, 512, part2);
  k_gred<<<76, 256, 0, stream>>>(part2, 1216, st2);

  // final
  k_final<<<2048, 256, 0, stream>>>(g2, x, Wfb, fb, st2, lg0, lbb0, out);
}

// Round 9
// 467.810 us; speedup vs baseline: 1.3935x; 1.3935x over previous
//
#include <hip/hip_runtime.h>
#include <hip/hip_bf16.h>
#include <math.h>

#define B_   2048
#define N_   38
#define E_   4
#define DIN_ 9
#define H0_  256
#define H1_  256
#define L0_  512
#define M_   (B_ * N_)

typedef short bf16x8 __attribute__((ext_vector_type(8)));
typedef float f32x4 __attribute__((ext_vector_type(4)));

// ---------- bf16 helpers ----------
struct __align__(8) bf4 { __hip_bfloat16 x, y, z, w; };

__device__ __forceinline__ float b2f(unsigned short u) {
  return __uint_as_float((unsigned)u << 16);
}
__device__ __forceinline__ unsigned short f2b(float f) {
  __hip_bfloat16 h = __float2bfloat16(f);
  return *(unsigned short*)&h;
}
__device__ __forceinline__ void st4v(__hip_bfloat16* p, float4 v) {
  bf4 o;
  o.x = __float2bfloat16(v.x); o.y = __float2bfloat16(v.y);
  o.z = __float2bfloat16(v.z); o.w = __float2bfloat16(v.w);
  *(bf4*)p = o;
}

static __device__ __forceinline__ float selc(const float4 v, int j) {
  return (j == 0) ? v.x : ((j == 1) ? v.y : ((j == 2) ? v.z : v.w));
}

// reduce over 16 consecutive lanes (lrow dimension)
__device__ __forceinline__ float rsum16(float v) {
  v += __shfl_xor(v, 1);
  v += __shfl_xor(v, 2);
  v += __shfl_xor(v, 4);
  v += __shfl_xor(v, 8);
  return v;
}
// reduce over all 64 lanes
__device__ __forceinline__ float rsum64(float v) {
  v += __shfl_xor(v, 1);
  v += __shfl_xor(v, 2);
  v += __shfl_xor(v, 4);
  v += __shfl_xor(v, 8);
  v += __shfl_xor(v, 16);
  v += __shfl_xor(v, 32);
  return v;
}

__device__ __forceinline__ void fma_tile12(const float* __restrict__ zr, float4 w,
                                           float (&acc)[4][12]) {
#pragma unroll
  for (int l4 = 0; l4 < 3; ++l4) {
    float4 zv = *(const float4*)&zr[l4 * 4];
#pragma unroll
    for (int j = 0; j < 4; ++j) {
      float wj = selc(w, j);
      acc[j][l4 * 4 + 0] = fmaf(zv.x, wj, acc[j][l4 * 4 + 0]);
      acc[j][l4 * 4 + 1] = fmaf(zv.y, wj, acc[j][l4 * 4 + 1]);
      acc[j][l4 * 4 + 2] = fmaf(zv.z, wj, acc[j][l4 * 4 + 2]);
      acc[j][l4 * 4 + 3] = fmaf(zv.w, wj, acc[j][l4 * 4 + 3]);
    }
  }
}

// wt0 fp32 [45][256]
__global__ void k_build_w0(const float* __restrict__ Ws, const float* __restrict__ We,
                           float* __restrict__ WT) {
  int i = blockIdx.x * 256 + threadIdx.x;
  if (i >= 45 * 256) return;
  int r = i / 256, c = i % 256;
  float v;
  if (r < 9) v = Ws[c * 9 + r];
  else { int rr = r - 9; int e = rr / 9, f = rr % 9; v = We[(c * 4 + e) * 9 + f]; }
  WT[i] = v;
}

// Wbig bf16 [1280][256]
__global__ void k_build_wbig(const float* __restrict__ Ws, const float* __restrict__ We,
                             unsigned short* __restrict__ WT) {
  int i = blockIdx.x * 256 + threadIdx.x;
  if (i >= 1280 * 256) return;
  int j = i / 256, f = i % 256;
  float v;
  if (j < 256) v = Ws[j * 256 + f];
  else { int jj = j - 256; int e = jj >> 8, c = jj & 255; v = We[(c * 4 + e) * 256 + f]; }
  WT[i] = f2b(v);
}

// Wl bf16 [512][256]
__global__ void k_build_wl(const float* __restrict__ W, unsigned short* __restrict__ WT) {
  int i = blockIdx.x * 256 + threadIdx.x;
  if (i >= 512 * 256) return;
  WT[i] = f2b(W[i]);
}

// Wfb bf16 [32][512]
__global__ void k_build_wf(const float* __restrict__ W, unsigned short* __restrict__ WT) {
  int i = blockIdx.x * 256 + threadIdx.x;
  if (i >= 32 * 512) return;
  int r = i / 512, k = i % 512;
  WT[i] = f2b(r < 18 ? W[r * 512 + k] : 0.f);
}

// partials reduce: part[nblk][76] -> st
__global__ __launch_bounds__(256) void k_gred(const float* __restrict__ part, int nblk,
                                              float* __restrict__ st) {
  const int j = blockIdx.x, tid = threadIdx.x;
  float s = 0.f;
  for (int i = tid; i < nblk; i += 256) s += part[(size_t)i * 76 + j];
#pragma unroll
  for (int off = 32; off; off >>= 1) s += __shfl_down(s, off);
  __shared__ float r[4];
  if ((tid & 63) == 0) r[tid >> 6] = s;
  __syncthreads();
  if (tid == 0) {
    float tot = r[0] + r[1] + r[2] + r[3];
    if (j < 38) st[j * 2] = tot;
    else st[(j - 38) * 2 + 1] = tot;
  }
}

// ---------------- gconv layer 0 (K=45), fp32 VALU, output bf16 + stats partials ----------------
__global__ __launch_bounds__(256) void k_gconv0(
    const float* __restrict__ adj, const float* __restrict__ x,
    const float* __restrict__ WT, const float* __restrict__ bs,
    const float* __restrict__ be, __hip_bfloat16* __restrict__ g,
    float* __restrict__ part) {
  __shared__ __align__(16) float adjF[E_ * N_ * N_];
  __shared__ __align__(16) float xc[45 * 48];
  __shared__ __align__(16) float arow[E_ * 48];
  __shared__ float lsum[48], lsq[48];
  const int b = blockIdx.x, tid = threadIdx.x;
  const size_t abase = (size_t)b * (E_ * N_ * N_);
  for (int i = tid; i < E_ * N_ * N_; i += 256) adjF[i] = adj[abase + i];
  for (int i = tid; i < N_ * DIN_; i += 256) {
    int n = i / DIN_;
    float v = x[(size_t)b * (N_ * DIN_) + i];
    xc[(i % DIN_) * 48 + n] = (n & 1) ? v : 0.f;   // MASK zeroes even rows
  }
  __syncthreads();
  for (int i = tid; i < E_ * N_; i += 256) {
    int e = i / N_, m = i % N_;
    const float* ar = &adjF[(e * N_ + m) * N_];
    float s = 0.f;
    for (int n = 0; n < N_; ++n) s += ar[n];
    arow[e * 48 + m] = s;
  }
  for (int i = tid; i < 36 * N_; i += 256) {
    int m = i % N_, ef = i / N_;
    int e = ef / 9, f = ef % 9;
    const float* ar = &adjF[(e * N_ + m) * N_];
    float s = 0.f;
    for (int n = 0; n < N_; ++n) s += ar[n] * xc[f * 48 + n];
    xc[(9 + ef) * 48 + m] = s;
  }
  __syncthreads();
  const int cg = tid & 63, mg = tid >> 6;
  const int c0 = cg * 4, mb = mg * 12;
  float acc[4][12];
#pragma unroll
  for (int j = 0; j < 4; ++j) {
    float bsv = bs[c0 + j];
    float b0 = be[(c0 + j) * 4 + 0], b1 = be[(c0 + j) * 4 + 1];
    float b2 = be[(c0 + j) * 4 + 2], b3 = be[(c0 + j) * 4 + 3];
#pragma unroll
    for (int l = 0; l < 12; ++l) {
      int m = mb + l;
      acc[j][l] = bsv + arow[0 * 48 + m] * b0 + arow[1 * 48 + m] * b1 +
                  arow[2 * 48 + m] * b2 + arow[3 * 48 + m] * b3;
    }
  }
  for (int k = 0; k < 45; ++k) {
    float4 w = *(const float4*)&WT[k * 256 + c0];
    fma_tile12(&xc[k * 48 + mb], w, acc);
  }
#pragma unroll
  for (int l = 0; l < 12; ++l) {
    int m = mb + l;
    float s = 0.f, q = 0.f;
    if (m < N_) {
      float4 o; o.x = acc[0][l]; o.y = acc[1][l]; o.z = acc[2][l]; o.w = acc[3][l];
      st4v(&g[((size_t)b * N_ + m) * H0_ + c0], o);
      s = o.x + o.y + o.z + o.w;
      q = o.x * o.x + o.y * o.y + o.z * o.z + o.w * o.w;
    }
    // all 64 lanes of this wave share m: full-wave reduce, exclusive m-range per wave
    s = rsum64(s);
    q = rsum64(q);
    if (cg == 0) { lsum[m] = s; lsq[m] = q; }
  }
  __syncthreads();
  if (tid < 38) {
    part[(size_t)b * 76 + tid] = lsum[tid];
    part[(size_t)b * 76 + 38 + tid] = lsq[tid];
  }
}

// ---------------- k_gemm: 128x256 MFMA GEMM with fused BN+ReLU on A ----------------
template <bool BIAS, bool STATS>
__global__ __launch_bounds__(512) void k_gemm(
    const unsigned short* __restrict__ A0, const unsigned short* __restrict__ Bw,
    const float* __restrict__ bias, const float* __restrict__ stIn,
    const float* __restrict__ gam, const float* __restrict__ bet, float cnt,
    unsigned short* __restrict__ Cout, int Cstride, float* __restrict__ part) {
  __shared__ __align__(16) unsigned short lA[128 * 32];
  __shared__ __align__(16) unsigned short lB[256 * 32];
  __shared__ float lbias[256];
  __shared__ float lsum[38], lsq[38];
  const int t = threadIdx.x;
  const int tileM = blockIdx.x, n_base = blockIdx.y * 256;
  if (BIAS && t < 256) lbias[t] = bias[n_base + t];
  if (STATS && t < 38) { lsum[t] = 0.f; lsq[t] = 0.f; }
  const int w = t >> 6, L = t & 63;
  const int wr = w >> 2, wc = w & 3;
  const int lrow = L & 15, quad = L >> 4;
  const int srow = t >> 2, sseg = (t & 3) * 8;
  const int nA = (tileM * 128 + srow) % 38;
  float aC, bC;
  {
    float mu = stIn[nA * 2] / cnt;
    float var = stIn[nA * 2 + 1] / cnt - mu * mu;
    aC = rsqrtf(var + 1e-5f) * gam[nA];
    bC = bet[nA] - mu * aC;
  }
  const unsigned short* aRow = A0 + (size_t)(tileM * 128 + srow) * 256 + sseg;
  f32x4 acc[4][4];
#pragma unroll
  for (int mt = 0; mt < 4; ++mt)
#pragma unroll
    for (int nt = 0; nt < 4; ++nt) acc[mt][nt] = (f32x4){0.f, 0.f, 0.f, 0.f};

  uint4 u = *(const uint4*)aRow;
  for (int ki = 0; ki < 8; ++ki) {
    // B async stage first (latency overlaps A VALU work)
#pragma unroll
    for (int r = 0; r < 2; ++r) {
      const unsigned short* gp = Bw + (size_t)(n_base + r * 128 + srow) * 256 + ki * 32 + sseg;
      __builtin_amdgcn_global_load_lds(
          (const __attribute__((address_space(1))) void*)gp,
          (__attribute__((address_space(3))) void*)(lB + r * 4096 + w * 512), 16, 0, 0);
    }
    uint4 un = u;
    if (ki < 7) un = *(const uint4*)(aRow + (ki + 1) * 32);
    // BN+ReLU + pack -> LDS
    {
      uint4 o;
      unsigned* up = (unsigned*)&u;
      unsigned* op = (unsigned*)&o;
#pragma unroll
      for (int j = 0; j < 4; ++j) {
        float lo = fmaxf(fmaf(b2f((unsigned short)(up[j] & 0xffff)), aC, bC), 0.f);
        float hi = fmaxf(fmaf(b2f((unsigned short)(up[j] >> 16)), aC, bC), 0.f);
        op[j] = (unsigned)f2b(lo) | ((unsigned)f2b(hi) << 16);
      }
      *(uint4*)&lA[srow * 32 + sseg] = o;
    }
    __syncthreads();
    bf16x8 af[4], bfr[4];
#pragma unroll
    for (int mt = 0; mt < 4; ++mt)
      af[mt] = *(const bf16x8*)&lA[(wr * 64 + mt * 16 + lrow) * 32 + quad * 8];
#pragma unroll
    for (int nt = 0; nt < 4; ++nt)
      bfr[nt] = *(const bf16x8*)&lB[(wc * 64 + nt * 16 + lrow) * 32 + quad * 8];
#pragma unroll
    for (int mt = 0; mt < 4; ++mt)
#pragma unroll
      for (int nt = 0; nt < 4; ++nt)
        acc[mt][nt] = __builtin_amdgcn_mfma_f32_16x16x32_bf16(af[mt], bfr[nt], acc[mt][nt], 0, 0, 0);
    __syncthreads();
    u = un;
  }
#pragma unroll
  for (int mt = 0; mt < 4; ++mt) {
#pragma unroll
    for (int reg = 0; reg < 4; ++reg) {
      const size_t row = (size_t)tileM * 128 + wr * 64 + mt * 16 + quad * 4 + reg;
      float sv = 0.f, qv = 0.f;
#pragma unroll
      for (int nt = 0; nt < 4; ++nt) {
        const int lcol = wc * 64 + nt * 16 + lrow;
        float v = acc[mt][nt][reg];
        if (BIAS) v += lbias[lcol];
        Cout[row * Cstride + n_base + lcol] = f2b(v);
        sv += v;
        qv += v * v;
      }
      if (STATS) {
        // 16 lrow-lanes share this row: shuffle-reduce, single lane atomics
        sv = rsum16(sv);
        qv = rsum16(qv);
        if (lrow == 0) {
          int n = (int)(row % 38);
          atomicAdd(&lsum[n], sv);
          atomicAdd(&lsq[n], qv);
        }
      }
    }
  }
  if (STATS) {
    __syncthreads();
    const int blk = blockIdx.y * gridDim.x + blockIdx.x;
    if (t < 38) {
      part[(size_t)blk * 76 + t] = lsum[t];
      part[(size_t)blk * 76 + 38 + t] = lsq[t];
    }
  }
}

// ---------------- k_hr: per-b contraction hr = adj_e x Y_e, + hs + bias + arow.be + stats ----------------
__global__ __launch_bounds__(256) void k_hr(
    const float* __restrict__ adj, const unsigned short* __restrict__ Y,
    const float* __restrict__ bs, const float* __restrict__ be,
    unsigned short* __restrict__ h2, int b_base, float* __restrict__ part) {
  __shared__ __align__(16) unsigned short adjE[4 * 48 * 64];
  __shared__ __align__(16) unsigned short Ybt[256 * 72];
  __shared__ float arowS[4 * 48];
  __shared__ float lsumW[4][48], lsqW[4][48];
  const int t = threadIdx.x;
  const int bl = blockIdx.x, b = b_base + bl;
  for (int i = t; i < 4 * 48 * 64 / 8; i += 256) ((uint4*)adjE)[i] = make_uint4(0, 0, 0, 0);
#pragma unroll
  for (int n = 38; n < 64; ++n) Ybt[t * 72 + n] = 0;
  __syncthreads();
  for (int i = t; i < 4 * 38 * 38; i += 256) {
    int e = i / 1444, r = i % 1444, m = r / 38, n = r % 38;
    adjE[(e * 48 + m) * 64 + n] = f2b(adj[(size_t)b * 5776 + i]);
  }
  __syncthreads();
  if (t < 152) {
    int e = t / 38, m = t % 38;
    float s = 0.f;
    for (int n = 0; n < 38; ++n) s += b2f(adjE[(e * 48 + m) * 64 + n]);
    arowS[e * 48 + m] = s;
  }
  const int w = t >> 6, L = t & 63;
  const int lrow = L & 15, quad = L >> 4;
  f32x4 acc[3][4];
#pragma unroll
  for (int mt = 0; mt < 3; ++mt)
#pragma unroll
    for (int nt = 0; nt < 4; ++nt) acc[mt][nt] = (f32x4){0.f, 0.f, 0.f, 0.f};
#pragma unroll 1
  for (int e = 0; e < 4; ++e) {
    __syncthreads();
    {
      const unsigned short* yp = Y + (size_t)bl * 38 * 1280 + 256 + e * 256 + t;
#pragma unroll
      for (int n = 0; n < 38; ++n) Ybt[t * 72 + n] = yp[(size_t)n * 1280];
    }
    __syncthreads();
#pragma unroll
    for (int kk = 0; kk < 2; ++kk) {
      bf16x8 bb[4];
#pragma unroll
      for (int nt = 0; nt < 4; ++nt)
        bb[nt] = *(const bf16x8*)&Ybt[(w * 64 + nt * 16 + lrow) * 72 + kk * 32 + quad * 8];
#pragma unroll
      for (int mt = 0; mt < 3; ++mt) {
        bf16x8 aa = *(const bf16x8*)&adjE[(e * 48 + mt * 16 + lrow) * 64 + kk * 32 + quad * 8];
#pragma unroll
        for (int nt = 0; nt < 4; ++nt)
          acc[mt][nt] = __builtin_amdgcn_mfma_f32_16x16x32_bf16(aa, bb[nt], acc[mt][nt], 0, 0, 0);
      }
    }
  }
#pragma unroll
  for (int mt = 0; mt < 3; ++mt) {
#pragma unroll
    for (int reg = 0; reg < 4; ++reg) {
      const int m = mt * 16 + quad * 4 + reg;
      float sv = 0.f, qv = 0.f;
      if (m < N_) {
        float a0 = arowS[0 * 48 + m], a1 = arowS[1 * 48 + m];
        float a2 = arowS[2 * 48 + m], a3 = arowS[3 * 48 + m];
#pragma unroll
        for (int nt = 0; nt < 4; ++nt) {
          const int col = w * 64 + nt * 16 + lrow;
          float hs = b2f(Y[(size_t)(bl * 38 + m) * 1280 + col]);
          float4 bev = *(const float4*)&be[col * 4];
          float v = acc[mt][nt][reg] + hs + bs[col] +
                    a0 * bev.x + a1 * bev.y + a2 * bev.z + a3 * bev.w;
          h2[((size_t)b * N_ + m) * 256 + col] = f2b(v);
          sv += v;
          qv += v * v;
        }
      }
      // 16 lrow-lanes share m; each wave covers m=0..47 exactly once -> no atomics
      sv = rsum16(sv);
      qv = rsum16(qv);
      if (lrow == 0) { lsumW[w][m] = sv; lsqW[w][m] = qv; }
    }
  }
  __syncthreads();
  if (t < 38) {
    part[(size_t)b * 76 + t] = lsumW[0][t] + lsumW[1][t] + lsumW[2][t] + lsumW[3][t];
    part[(size_t)b * 76 + 38 + t] = lsqW[0][t] + lsqW[1][t] + lsqW[2][t] + lsqW[3][t];
  }
}

// ---------------- final: MFMA 512->18 + coupling + logdet, BN2+ReLU fused ----------------
__global__ __launch_bounds__(256) void k_final(
    const unsigned short* __restrict__ g2, const float* __restrict__ x,
    const unsigned short* __restrict__ Wfb, const float* __restrict__ fb,
    const float* __restrict__ st, const float* __restrict__ gam,
    const float* __restrict__ bet, float* __restrict__ out) {
  __shared__ __align__(16) unsigned short hA[48 * 520];
  __shared__ float lgS[48 * 20];
  __shared__ float aS[N_], bS[N_], fbS[20], red[4];
  const int b = blockIdx.x, tid = threadIdx.x;
  if (tid < N_) {
    const float cnt = 2048.f * 512.f;
    float mu = st[tid * 2] / cnt;
    float var = st[tid * 2 + 1] / cnt - mu * mu;
    float a = rsqrtf(var + 1e-5f) * gam[tid];
    aS[tid] = a;
    bS[tid] = bet[tid] - mu * a;
  }
  if (tid >= 64 && tid < 82) fbS[tid - 64] = fb[tid - 64];
  __syncthreads();
  for (int i = tid; i < N_ * 64; i += 256) {
    int n = i >> 6, seg = (i & 63) * 8;
    uint4 u = *(const uint4*)&g2[((size_t)b * N_ + n) * 512 + seg];
    float a = aS[n], bb = bS[n];
    float v[8];
    v[0] = b2f((unsigned short)(u.x & 0xffff)); v[1] = b2f((unsigned short)(u.x >> 16));
    v[2] = b2f((unsigned short)(u.y & 0xffff)); v[3] = b2f((unsigned short)(u.y >> 16));
    v[4] = b2f((unsigned short)(u.z & 0xffff)); v[5] = b2f((unsigned short)(u.z >> 16));
    v[6] = b2f((unsigned short)(u.w & 0xffff)); v[7] = b2f((unsigned short)(u.w >> 16));
#pragma unroll
    for (int j = 0; j < 8; ++j) v[j] = fmaxf(fmaf(v[j], a, bb), 0.f);
    uint4 o;
    o.x = (unsigned)f2b(v[0]) | ((unsigned)f2b(v[1]) << 16);
    o.y = (unsigned)f2b(v[2]) | ((unsigned)f2b(v[3]) << 16);
    o.z = (unsigned)f2b(v[4]) | ((unsigned)f2b(v[5]) << 16);
    o.w = (unsigned)f2b(v[6]) | ((unsigned)f2b(v[7]) << 16);
    *(uint4*)&hA[n * 520 + seg] = o;
  }
  for (int i = tid; i < 10 * 64; i += 256) {
    int n = 38 + (i >> 6), seg = (i & 63) * 8;
    *(uint4*)&hA[n * 520 + seg] = make_uint4(0, 0, 0, 0);
  }
  __syncthreads();
  const int w = tid >> 6, L = tid & 63;
  const int lrow = L & 15, quad = L >> 4;
  if (w < 3) {
    f32x4 acc0 = (f32x4){0.f, 0.f, 0.f, 0.f}, acc1 = (f32x4){0.f, 0.f, 0.f, 0.f};
#pragma unroll
    for (int ki = 0; ki < 16; ++ki) {
      bf16x8 af = *(const bf16x8*)&hA[(w * 16 + lrow) * 520 + ki * 32 + quad * 8];
      bf16x8 b0 = *(const bf16x8*)&Wfb[(size_t)lrow * 512 + ki * 32 + quad * 8];
      bf16x8 b1 = *(const bf16x8*)&Wfb[(size_t)(16 + lrow) * 512 + ki * 32 + quad * 8];
      acc0 = __builtin_amdgcn_mfma_f32_16x16x32_bf16(af, b0, acc0, 0, 0, 0);
      acc1 = __builtin_amdgcn_mfma_f32_16x16x32_bf16(af, b1, acc1, 0, 0, 0);
    }
#pragma unroll
    for (int reg = 0; reg < 4; ++reg) {
      int m = w * 16 + quad * 4 + reg;
      if (m < N_) {
        lgS[m * 20 + lrow] = acc0[reg] + fbS[lrow];
        if (lrow < 2) lgS[m * 20 + 16 + lrow] = acc1[reg] + fbS[16 + lrow];
      }
    }
  }
  __syncthreads();
  float ls = 0.f;
  for (int ii = tid; ii < 342; ii += 256) {
    int mm = ii / 9, d = ii % 9;
    float sl = lgS[mm * 20 + d];
    float tv = lgS[mm * 20 + 9 + d];
    float xv = x[((size_t)b * N_ + mm) * 9 + d];
    float sg = 1.f / (1.f + expf(-sl));
    float o = (mm & 1) ? xv : (xv + tv) * sg;
    out[((size_t)b * N_ + mm) * 9 + d] = o;
    ls += (sl >= 0.f) ? -log1pf(expf(-sl)) : (sl - log1pf(expf(sl)));
  }
#pragma unroll
  for (int off = 32; off; off >>= 1) ls += __shfl_down(ls, off);
  if (L == 0) red[w] = ls;
  __syncthreads();
  if (tid == 0) out[(size_t)B_ * 342 + b] = red[0] + red[1] + red[2] + red[3];
}

extern "C" void kernel_launch(void* const* d_in, const int* in_sizes, int n_in,
                              void* d_out, int out_size, void* d_ws, size_t ws_size,
                              hipStream_t stream) {
  (void)in_sizes; (void)n_in; (void)out_size; (void)ws_size;
  const float* adj  = (const float*)d_in[0];
  const float* x    = (const float*)d_in[1];
  const float* cWs0 = (const float*)d_in[2];
  const float* cbs0 = (const float*)d_in[3];
  const float* cWe0 = (const float*)d_in[4];
  const float* cbe0 = (const float*)d_in[5];
  const float* cg0  = (const float*)d_in[6];
  const float* cb0  = (const float*)d_in[7];
  const float* cWs1 = (const float*)d_in[8];
  const float* cbs1 = (const float*)d_in[9];
  const float* cWe1 = (const float*)d_in[10];
  const float* cbe1 = (const float*)d_in[11];
  const float* cg1  = (const float*)d_in[12];
  const float* cb1  = (const float*)d_in[13];
  const float* lW0  = (const float*)d_in[14];
  const float* lb0  = (const float*)d_in[15];
  const float* lg0  = (const float*)d_in[16];
  const float* lbb0 = (const float*)d_in[17];
  const float* fW   = (const float*)d_in[18];
  const float* fb   = (const float*)d_in[19];
  float* out = (float*)d_out;

  // ---- workspace layout ----
  char* p = (char*)d_ws;
  float* stats = (float*)p;                     p += 1024;
  float* wt0   = (float*)p;                     p += 45 * 256 * 4;
  unsigned short* Wfb  = (unsigned short*)p;    p += 32 * 512 * 2;
  unsigned short* Wbig = (unsigned short*)p;    p += 1280 * 256 * 2;
  unsigned short* Wl   = (unsigned short*)p;    p += 512 * 256 * 2;
  float* part0 = (float*)p;                     p += 2048 * 76 * 4;
  float* part1 = (float*)p;                     p += 2048 * 76 * 4;
  float* part2 = (float*)p;                     p += 1216 * 76 * 4;
  unsigned short* g0   = (unsigned short*)p;    p += (size_t)M_ * 256 * 2;
  unsigned short* h2   = (unsigned short*)p;    p += (size_t)M_ * 256 * 2;
  unsigned short* big  = (unsigned short*)p;    // Y-half (99.6MB) then g2 (79.7MB)
  unsigned short* Ybuf = big;
  unsigned short* g2   = big;

  float* st0 = stats;
  float* st1 = stats + 76;
  float* st2 = stats + 152;

  k_build_w0<<<45, 256, 0, stream>>>(cWs0, cWe0, wt0);
  k_build_wbig<<<1280, 256, 0, stream>>>(cWs1, cWe1, Wbig);
  k_build_wl<<<512, 256, 0, stream>>>(lW0, Wl);
  k_build_wf<<<64, 256, 0, stream>>>(fW, Wfb);

  // layer 0 (writes g0 raw + stats partials, no atomics)
  k_gconv0<<<2048, 256, 0, stream>>>(adj, x, wt0, cbs0, cbe0, (__hip_bfloat16*)g0, part0);
  k_gred<<<76, 256, 0, stream>>>(part0, 2048, st0);

  // layer 1: Y = BN0ReLU(g0) * Wbig^T, then per-b adj contraction; 2 halves
  for (int hh = 0; hh < 2; ++hh) {
    k_gemm<false, false><<<dim3(304, 5), 512, 0, stream>>>(
        g0 + (size_t)hh * (M_ / 2) * 256, Wbig, (const float*)nullptr,
        st0, cg0, cb0, 2048.f * 256.f, Ybuf, 1280, (float*)nullptr);
    k_hr<<<1024, 256, 0, stream>>>(adj, Ybuf, cbs1, cbe1, h2, hh * 1024, part1);
  }
  k_gred<<<76, 256, 0, stream>>>(part1, 2048, st1);

  // layer 2: g2 = BN1ReLU(h2) * Wl^T + lb0  (+ stats partials)
  k_gemm<true, true><<<dim3(608, 2), 512, 0, stream>>>(
      h2, Wl, lb0, st1, cg1, cb1, 2048.f * 256.f, g2, 512, part2);
  k_gred<<<76, 256, 0, stream>>>(part2, 1216, st2);

  // final
  k_final<<<2048, 256, 0, stream>>>(g2, x, Wfb, fb, st2, lg0, lbb0, out);
}

// Round 10
// 438.722 us; speedup vs baseline: 1.4859x; 1.0663x over previous
//
#include <hip/hip_runtime.h>
#include <hip/hip_bf16.h>
#include <math.h>

#define B_   2048
#define N_   38
#define E_   4
#define DIN_ 9
#define H0_  256
#define H1_  256
#define L0_  512
#define M_   (B_ * N_)

typedef short bf16x8 __attribute__((ext_vector_type(8)));
typedef float f32x4 __attribute__((ext_vector_type(4)));

// ---------- bf16 helpers ----------
struct __align__(8) bf4 { __hip_bfloat16 x, y, z, w; };

__device__ __forceinline__ float b2f(unsigned short u) {
  return __uint_as_float((unsigned)u << 16);
}
__device__ __forceinline__ unsigned short f2b(float f) {
  __hip_bfloat16 h = __float2bfloat16(f);
  return *(unsigned short*)&h;
}

// reduce over 16 consecutive lanes (lrow dimension)
__device__ __forceinline__ float rsum16(float v) {
  v += __shfl_xor(v, 1);
  v += __shfl_xor(v, 2);
  v += __shfl_xor(v, 4);
  v += __shfl_xor(v, 8);
  return v;
}

// Wg0 bf16 [256 c][96 k]: k<64 -> z-part (e=k>>4,f=k&15: f<9 We0[(c*4+e)][f], f==9 be0[c*4+e]);
// k in [64,80) -> x-part (f=k-64: f<9 Ws0[c][f], f==9 bs0[c]); else 0.
__global__ void k_build_wg0(const float* __restrict__ Ws, const float* __restrict__ bs,
                            const float* __restrict__ We, const float* __restrict__ be,
                            unsigned short* __restrict__ WT) {
  int i = blockIdx.x * 256 + threadIdx.x;
  if (i >= 256 * 96) return;
  int c = i / 96, k = i % 96;
  float v = 0.f;
  if (k < 64) {
    int e = k >> 4, f = k & 15;
    if (f < 9) v = We[(c * 4 + e) * 9 + f];
    else if (f == 9) v = be[c * 4 + e];
  } else if (k < 80) {
    int f = k - 64;
    if (f < 9) v = Ws[c * 9 + f];
    else if (f == 9) v = bs[c];
  }
  WT[i] = f2b(v);
}

// Wbig bf16 [1280][256]
__global__ void k_build_wbig(const float* __restrict__ Ws, const float* __restrict__ We,
                             unsigned short* __restrict__ WT) {
  int i = blockIdx.x * 256 + threadIdx.x;
  if (i >= 1280 * 256) return;
  int j = i / 256, f = i % 256;
  float v;
  if (j < 256) v = Ws[j * 256 + f];
  else { int jj = j - 256; int e = jj >> 8, c = jj & 255; v = We[(c * 4 + e) * 256 + f]; }
  WT[i] = f2b(v);
}

// Wl bf16 [512][256]
__global__ void k_build_wl(const float* __restrict__ W, unsigned short* __restrict__ WT) {
  int i = blockIdx.x * 256 + threadIdx.x;
  if (i >= 512 * 256) return;
  WT[i] = f2b(W[i]);
}

// Wfb bf16 [32][512]
__global__ void k_build_wf(const float* __restrict__ W, unsigned short* __restrict__ WT) {
  int i = blockIdx.x * 256 + threadIdx.x;
  if (i >= 32 * 512) return;
  int r = i / 512, k = i % 512;
  WT[i] = f2b(r < 18 ? W[r * 512 + k] : 0.f);
}

// partials reduce: part[nblk][76] -> st
__global__ __launch_bounds__(256) void k_gred(const float* __restrict__ part, int nblk,
                                              float* __restrict__ st) {
  const int j = blockIdx.x, tid = threadIdx.x;
  float s = 0.f;
  for (int i = tid; i < nblk; i += 256) s += part[(size_t)i * 76 + j];
#pragma unroll
  for (int off = 32; off; off >>= 1) s += __shfl_down(s, off);
  __shared__ float r[4];
  if ((tid & 63) == 0) r[tid >> 6] = s;
  __syncthreads();
  if (tid == 0) {
    float tot = r[0] + r[1] + r[2] + r[3];
    if (j < 38) st[j * 2] = tot;
    else st[(j - 38) * 2 + 1] = tot;
  }
}

// ---------------- gconv layer 0, full MFMA (z + main GEMM), bias/be folded into Wg0 ----------------
// One block per b, 256 thr (4 waves). Output g0 raw bf16 + stats partials (no atomics).
__global__ __launch_bounds__(256) void k_gconv0(
    const float* __restrict__ adj, const float* __restrict__ x,
    const unsigned short* __restrict__ Wg0, unsigned short* __restrict__ g,
    float* __restrict__ part) {
  __shared__ __align__(16) unsigned short adjB[4 * 48 * 64];  // [e][m(48)][n(64)] 24.6KB
  __shared__ __align__(16) unsigned short zB[48 * 64];        // [m][e*16+f] 6KB
  __shared__ __align__(16) unsigned short xLA[64 * 32];       // [m][f(32)] 4KB (A chunk2)
  __shared__ __align__(16) unsigned short xLB[16 * 64];       // [f][n(64)] 2KB (B of z-mfma)
  __shared__ float lsumW[4][48], lsqW[4][48];
  const int b = blockIdx.x, t = threadIdx.x;
  const uint4 z4 = make_uint4(0, 0, 0, 0);
  // zero fills
  for (int i = t; i < 4 * 48 * 64 / 8; i += 256) ((uint4*)adjB)[i] = z4;
  for (int i = t; i < 64 * 32 / 8; i += 256) ((uint4*)xLA)[i] = z4;
  for (int i = t; i < 16 * 64 / 8; i += 256) ((uint4*)xLB)[i] = z4;
  __syncthreads();
  // stage adj -> bf16 [e][m][n]
  for (int i = t; i < 4 * 38 * 38; i += 256) {
    int e = i / 1444, r = i % 1444, m = r / 38, n = r % 38;
    adjB[(e * 48 + m) * 64 + n] = f2b(adj[(size_t)b * 5776 + i]);
  }
  // stage x (masked) -> xLA [m][f], xLB [f][n]; ones col f=9 (unmasked)
  for (int i = t; i < 342; i += 256) {
    int m = i / 9, f = i % 9;
    float v = x[(size_t)b * 342 + i];
    unsigned short bv = f2b((m & 1) ? v : 0.f);
    xLA[m * 32 + f] = bv;
    xLB[f * 64 + m] = bv;
  }
  if (t < 38) {
    unsigned short one = f2b(1.f);
    xLA[t * 32 + 9] = one;
    xLB[9 * 64 + t] = one;
  }
  __syncthreads();
  const int w = t >> 6, L = t & 63;
  const int lrow = L & 15, quad = L >> 4;
  // ---- z-MFMA: wave w computes e=w; z'[m][f] (f=9 -> arow)
  {
    f32x4 za[3];
#pragma unroll
    for (int mt = 0; mt < 3; ++mt) za[mt] = (f32x4){0.f, 0.f, 0.f, 0.f};
#pragma unroll
    for (int kk = 0; kk < 2; ++kk) {
      bf16x8 bb = *(const bf16x8*)&xLB[lrow * 64 + kk * 32 + quad * 8];
#pragma unroll
      for (int mt = 0; mt < 3; ++mt) {
        bf16x8 aa = *(const bf16x8*)&adjB[(w * 48 + mt * 16 + lrow) * 64 + kk * 32 + quad * 8];
        za[mt] = __builtin_amdgcn_mfma_f32_16x16x32_bf16(aa, bb, za[mt], 0, 0, 0);
      }
    }
#pragma unroll
    for (int mt = 0; mt < 3; ++mt)
#pragma unroll
      for (int reg = 0; reg < 4; ++reg)
        zB[(mt * 16 + quad * 4 + reg) * 64 + w * 16 + lrow] = f2b(za[mt][reg]);
  }
  __syncthreads();
  // ---- main GEMM: A = [zB(64) | xLA(32)] (K=96), B = Wg0 from global/L2
  f32x4 acc[3][4];
#pragma unroll
  for (int mt = 0; mt < 3; ++mt)
#pragma unroll
    for (int nt = 0; nt < 4; ++nt) acc[mt][nt] = (f32x4){0.f, 0.f, 0.f, 0.f};
#pragma unroll
  for (int kc = 0; kc < 3; ++kc) {
    bf16x8 af[3];
#pragma unroll
    for (int mt = 0; mt < 3; ++mt)
      af[mt] = (kc < 2)
                   ? *(const bf16x8*)&zB[(mt * 16 + lrow) * 64 + kc * 32 + quad * 8]
                   : *(const bf16x8*)&xLA[(mt * 16 + lrow) * 32 + quad * 8];
#pragma unroll
    for (int nt = 0; nt < 4; ++nt) {
      const int c = w * 64 + nt * 16 + lrow;
      bf16x8 bf_ = *(const bf16x8*)&Wg0[(size_t)c * 96 + kc * 32 + quad * 8];
#pragma unroll
      for (int mt = 0; mt < 3; ++mt)
        acc[mt][nt] = __builtin_amdgcn_mfma_f32_16x16x32_bf16(af[mt], bf_, acc[mt][nt], 0, 0, 0);
    }
  }
  // ---- epilogue: store + stats (no atomics; wave covers m 0..47 once)
#pragma unroll
  for (int mt = 0; mt < 3; ++mt) {
#pragma unroll
    for (int reg = 0; reg < 4; ++reg) {
      const int m = mt * 16 + quad * 4 + reg;
      float sv = 0.f, qv = 0.f;
      if (m < N_) {
#pragma unroll
        for (int nt = 0; nt < 4; ++nt) {
          const int c = w * 64 + nt * 16 + lrow;
          float v = acc[mt][nt][reg];
          g[((size_t)b * N_ + m) * 256 + c] = f2b(v);
          sv += v;
          qv += v * v;
        }
      }
      sv = rsum16(sv);
      qv = rsum16(qv);
      if (lrow == 0) { lsumW[w][m] = sv; lsqW[w][m] = qv; }
    }
  }
  __syncthreads();
  if (t < 38) {
    part[(size_t)b * 76 + t] = lsumW[0][t] + lsumW[1][t] + lsumW[2][t] + lsumW[3][t];
    part[(size_t)b * 76 + 38 + t] = lsqW[0][t] + lsqW[1][t] + lsqW[2][t] + lsqW[3][t];
  }
}

// ---------------- k_gemm: 128x256 MFMA GEMM with fused BN+ReLU on A ----------------
template <bool BIAS, bool STATS>
__global__ __launch_bounds__(512) void k_gemm(
    const unsigned short* __restrict__ A0, const unsigned short* __restrict__ Bw,
    const float* __restrict__ bias, const float* __restrict__ stIn,
    const float* __restrict__ gam, const float* __restrict__ bet, float cnt,
    unsigned short* __restrict__ Cout, int Cstride, float* __restrict__ part) {
  __shared__ __align__(16) unsigned short lA[128 * 32];
  __shared__ __align__(16) unsigned short lB[256 * 32];
  __shared__ float lbias[256];
  __shared__ float lsum[38], lsq[38];
  const int t = threadIdx.x;
  const int tileM = blockIdx.x, n_base = blockIdx.y * 256;
  if (BIAS && t < 256) lbias[t] = bias[n_base + t];
  if (STATS && t < 38) { lsum[t] = 0.f; lsq[t] = 0.f; }
  const int w = t >> 6, L = t & 63;
  const int wr = w >> 2, wc = w & 3;
  const int lrow = L & 15, quad = L >> 4;
  const int srow = t >> 2, sseg = (t & 3) * 8;
  const int nA = (tileM * 128 + srow) % 38;
  float aC, bC;
  {
    float mu = stIn[nA * 2] / cnt;
    float var = stIn[nA * 2 + 1] / cnt - mu * mu;
    aC = rsqrtf(var + 1e-5f) * gam[nA];
    bC = bet[nA] - mu * aC;
  }
  const unsigned short* aRow = A0 + (size_t)(tileM * 128 + srow) * 256 + sseg;
  f32x4 acc[4][4];
#pragma unroll
  for (int mt = 0; mt < 4; ++mt)
#pragma unroll
    for (int nt = 0; nt < 4; ++nt) acc[mt][nt] = (f32x4){0.f, 0.f, 0.f, 0.f};

  uint4 u = *(const uint4*)aRow;
  for (int ki = 0; ki < 8; ++ki) {
#pragma unroll
    for (int r = 0; r < 2; ++r) {
      const unsigned short* gp = Bw + (size_t)(n_base + r * 128 + srow) * 256 + ki * 32 + sseg;
      __builtin_amdgcn_global_load_lds(
          (const __attribute__((address_space(1))) void*)gp,
          (__attribute__((address_space(3))) void*)(lB + r * 4096 + w * 512), 16, 0, 0);
    }
    uint4 un = u;
    if (ki < 7) un = *(const uint4*)(aRow + (ki + 1) * 32);
    {
      uint4 o;
      unsigned* up = (unsigned*)&u;
      unsigned* op = (unsigned*)&o;
#pragma unroll
      for (int j = 0; j < 4; ++j) {
        float lo = fmaxf(fmaf(b2f((unsigned short)(up[j] & 0xffff)), aC, bC), 0.f);
        float hi = fmaxf(fmaf(b2f((unsigned short)(up[j] >> 16)), aC, bC), 0.f);
        op[j] = (unsigned)f2b(lo) | ((unsigned)f2b(hi) << 16);
      }
      *(uint4*)&lA[srow * 32 + sseg] = o;
    }
    __syncthreads();
    bf16x8 af[4], bfr[4];
#pragma unroll
    for (int mt = 0; mt < 4; ++mt)
      af[mt] = *(const bf16x8*)&lA[(wr * 64 + mt * 16 + lrow) * 32 + quad * 8];
#pragma unroll
    for (int nt = 0; nt < 4; ++nt)
      bfr[nt] = *(const bf16x8*)&lB[(wc * 64 + nt * 16 + lrow) * 32 + quad * 8];
#pragma unroll
    for (int mt = 0; mt < 4; ++mt)
#pragma unroll
      for (int nt = 0; nt < 4; ++nt)
        acc[mt][nt] = __builtin_amdgcn_mfma_f32_16x16x32_bf16(af[mt], bfr[nt], acc[mt][nt], 0, 0, 0);
    __syncthreads();
    u = un;
  }
#pragma unroll
  for (int mt = 0; mt < 4; ++mt) {
#pragma unroll
    for (int reg = 0; reg < 4; ++reg) {
      const size_t row = (size_t)tileM * 128 + wr * 64 + mt * 16 + quad * 4 + reg;
      float sv = 0.f, qv = 0.f;
#pragma unroll
      for (int nt = 0; nt < 4; ++nt) {
        const int lcol = wc * 64 + nt * 16 + lrow;
        float v = acc[mt][nt][reg];
        if (BIAS) v += lbias[lcol];
        Cout[row * Cstride + n_base + lcol] = f2b(v);
        sv += v;
        qv += v * v;
      }
      if (STATS) {
        sv = rsum16(sv);
        qv = rsum16(qv);
        if (lrow == 0) {
          int n = (int)(row % 38);
          atomicAdd(&lsum[n], sv);
          atomicAdd(&lsq[n], qv);
        }
      }
    }
  }
  if (STATS) {
    __syncthreads();
    const int blk = blockIdx.y * gridDim.x + blockIdx.x;
    if (t < 38) {
      part[(size_t)blk * 76 + t] = lsum[t];
      part[(size_t)blk * 76 + 38 + t] = lsq[t];
    }
  }
}

// ---------------- k_hr: per-b contraction hr = adj_e x Y_e, + hs + bias + arow.be + stats ----------------
__global__ __launch_bounds__(256) void k_hr(
    const float* __restrict__ adj, const unsigned short* __restrict__ Y,
    const float* __restrict__ bs, const float* __restrict__ be,
    unsigned short* __restrict__ h2, int b_base, float* __restrict__ part) {
  __shared__ __align__(16) unsigned short adjE[4 * 48 * 64];
  __shared__ __align__(16) unsigned short Ybt[256 * 72];
  __shared__ float arowS[4 * 48];
  __shared__ float lsumW[4][48], lsqW[4][48];
  const int t = threadIdx.x;
  const int bl = blockIdx.x, b = b_base + bl;
  for (int i = t; i < 4 * 48 * 64 / 8; i += 256) ((uint4*)adjE)[i] = make_uint4(0, 0, 0, 0);
#pragma unroll
  for (int n = 38; n < 64; ++n) Ybt[t * 72 + n] = 0;
  __syncthreads();
  for (int i = t; i < 4 * 38 * 38; i += 256) {
    int e = i / 1444, r = i % 1444, m = r / 38, n = r % 38;
    adjE[(e * 48 + m) * 64 + n] = f2b(adj[(size_t)b * 5776 + i]);
  }
  __syncthreads();
  if (t < 152) {
    int e = t / 38, m = t % 38;
    float s = 0.f;
    for (int n = 0; n < 38; ++n) s += b2f(adjE[(e * 48 + m) * 64 + n]);
    arowS[e * 48 + m] = s;
  }
  const int w = t >> 6, L = t & 63;
  const int lrow = L & 15, quad = L >> 4;
  f32x4 acc[3][4];
#pragma unroll
  for (int mt = 0; mt < 3; ++mt)
#pragma unroll
    for (int nt = 0; nt < 4; ++nt) acc[mt][nt] = (f32x4){0.f, 0.f, 0.f, 0.f};
#pragma unroll 1
  for (int e = 0; e < 4; ++e) {
    __syncthreads();
    {
      const unsigned short* yp = Y + (size_t)bl * 38 * 1280 + 256 + e * 256 + t;
#pragma unroll
      for (int n = 0; n < 38; ++n) Ybt[t * 72 + n] = yp[(size_t)n * 1280];
    }
    __syncthreads();
#pragma unroll
    for (int kk = 0; kk < 2; ++kk) {
      bf16x8 bb[4];
#pragma unroll
      for (int nt = 0; nt < 4; ++nt)
        bb[nt] = *(const bf16x8*)&Ybt[(w * 64 + nt * 16 + lrow) * 72 + kk * 32 + quad * 8];
#pragma unroll
      for (int mt = 0; mt < 3; ++mt) {
        bf16x8 aa = *(const bf16x8*)&adjE[(e * 48 + mt * 16 + lrow) * 64 + kk * 32 + quad * 8];
#pragma unroll
        for (int nt = 0; nt < 4; ++nt)
          acc[mt][nt] = __builtin_amdgcn_mfma_f32_16x16x32_bf16(aa, bb[nt], acc[mt][nt], 0, 0, 0);
      }
    }
  }
#pragma unroll
  for (int mt = 0; mt < 3; ++mt) {
#pragma unroll
    for (int reg = 0; reg < 4; ++reg) {
      const int m = mt * 16 + quad * 4 + reg;
      float sv = 0.f, qv = 0.f;
      if (m < N_) {
        float a0 = arowS[0 * 48 + m], a1 = arowS[1 * 48 + m];
        float a2 = arowS[2 * 48 + m], a3 = arowS[3 * 48 + m];
#pragma unroll
        for (int nt = 0; nt < 4; ++nt) {
          const int col = w * 64 + nt * 16 + lrow;
          float hs = b2f(Y[(size_t)(bl * 38 + m) * 1280 + col]);
          float4 bev = *(const float4*)&be[col * 4];
          float v = acc[mt][nt][reg] + hs + bs[col] +
                    a0 * bev.x + a1 * bev.y + a2 * bev.z + a3 * bev.w;
          h2[((size_t)b * N_ + m) * 256 + col] = f2b(v);
          sv += v;
          qv += v * v;
        }
      }
      sv = rsum16(sv);
      qv = rsum16(qv);
      if (lrow == 0) { lsumW[w][m] = sv; lsqW[w][m] = qv; }
    }
  }
  __syncthreads();
  if (t < 38) {
    part[(size_t)b * 76 + t] = lsumW[0][t] + lsumW[1][t] + lsumW[2][t] + lsumW[3][t];
    part[(size_t)b * 76 + 38 + t] = lsqW[0][t] + lsqW[1][t] + lsqW[2][t] + lsqW[3][t];
  }
}

// ---------------- final: MFMA 512->18 + coupling + logdet, BN2+ReLU fused ----------------
__global__ __launch_bounds__(256) void k_final(
    const unsigned short* __restrict__ g2, const float* __restrict__ x,
    const unsigned short* __restrict__ Wfb, const float* __restrict__ fb,
    const float* __restrict__ st, const float* __restrict__ gam,
    const float* __restrict__ bet, float* __restrict__ out) {
  __shared__ __align__(16) unsigned short hA[48 * 520];
  __shared__ float lgS[48 * 20];
  __shared__ float aS[N_], bS[N_], fbS[20], red[4];
  const int b = blockIdx.x, tid = threadIdx.x;
  if (tid < N_) {
    const float cnt = 2048.f * 512.f;
    float mu = st[tid * 2] / cnt;
    float var = st[tid * 2 + 1] / cnt - mu * mu;
    float a = rsqrtf(var + 1e-5f) * gam[tid];
    aS[tid] = a;
    bS[tid] = bet[tid] - mu * a;
  }
  if (tid >= 64 && tid < 82) fbS[tid - 64] = fb[tid - 64];
  __syncthreads();
  for (int i = tid; i < N_ * 64; i += 256) {
    int n = i >> 6, seg = (i & 63) * 8;
    uint4 u = *(const uint4*)&g2[((size_t)b * N_ + n) * 512 + seg];
    float a = aS[n], bb = bS[n];
    float v[8];
    v[0] = b2f((unsigned short)(u.x & 0xffff)); v[1] = b2f((unsigned short)(u.x >> 16));
    v[2] = b2f((unsigned short)(u.y & 0xffff)); v[3] = b2f((unsigned short)(u.y >> 16));
    v[4] = b2f((unsigned short)(u.z & 0xffff)); v[5] = b2f((unsigned short)(u.z >> 16));
    v[6] = b2f((unsigned short)(u.w & 0xffff)); v[7] = b2f((unsigned short)(u.w >> 16));
#pragma unroll
    for (int j = 0; j < 8; ++j) v[j] = fmaxf(fmaf(v[j], a, bb), 0.f);
    uint4 o;
    o.x = (unsigned)f2b(v[0]) | ((unsigned)f2b(v[1]) << 16);
    o.y = (unsigned)f2b(v[2]) | ((unsigned)f2b(v[3]) << 16);
    o.z = (unsigned)f2b(v[4]) | ((unsigned)f2b(v[5]) << 16);
    o.w = (unsigned)f2b(v[6]) | ((unsigned)f2b(v[7]) << 16);
    *(uint4*)&hA[n * 520 + seg] = o;
  }
  for (int i = tid; i < 10 * 64; i += 256) {
    int n = 38 + (i >> 6), seg = (i & 63) * 8;
    *(uint4*)&hA[n * 520 + seg] = make_uint4(0, 0, 0, 0);
  }
  __syncthreads();
  const int w = tid >> 6, L = tid & 63;
  const int lrow = L & 15, quad = L >> 4;
  if (w < 3) {
    f32x4 acc0 = (f32x4){0.f, 0.f, 0.f, 0.f}, acc1 = (f32x4){0.f, 0.f, 0.f, 0.f};
#pragma unroll
    for (int ki = 0; ki < 16; ++ki) {
      bf16x8 af = *(const bf16x8*)&hA[(w * 16 + lrow) * 520 + ki * 32 + quad * 8];
      bf16x8 b0 = *(const bf16x8*)&Wfb[(size_t)lrow * 512 + ki * 32 + quad * 8];
      bf16x8 b1 = *(const bf16x8*)&Wfb[(size_t)(16 + lrow) * 512 + ki * 32 + quad * 8];
      acc0 = __builtin_amdgcn_mfma_f32_16x16x32_bf16(af, b0, acc0, 0, 0, 0);
      acc1 = __builtin_amdgcn_mfma_f32_16x16x32_bf16(af, b1, acc1, 0, 0, 0);
    }
#pragma unroll
    for (int reg = 0; reg < 4; ++reg) {
      int m = w * 16 + quad * 4 + reg;
      if (m < N_) {
        lgS[m * 20 + lrow] = acc0[reg] + fbS[lrow];
        if (lrow < 2) lgS[m * 20 + 16 + lrow] = acc1[reg] + fbS[16 + lrow];
      }
    }
  }
  __syncthreads();
  float ls = 0.f;
  for (int ii = tid; ii < 342; ii += 256) {
    int mm = ii / 9, d = ii % 9;
    float sl = lgS[mm * 20 + d];
    float tv = lgS[mm * 20 + 9 + d];
    float xv = x[((size_t)b * N_ + mm) * 9 + d];
    float sg = 1.f / (1.f + expf(-sl));
    float o = (mm & 1) ? xv : (xv + tv) * sg;
    out[((size_t)b * N_ + mm) * 9 + d] = o;
    ls += (sl >= 0.f) ? -log1pf(expf(-sl)) : (sl - log1pf(expf(sl)));
  }
#pragma unroll
  for (int off = 32; off; off >>= 1) ls += __shfl_down(ls, off);
  if (L == 0) red[w] = ls;
  __syncthreads();
  if (tid == 0) out[(size_t)B_ * 342 + b] = red[0] + red[1] + red[2] + red[3];
}

extern "C" void kernel_launch(void* const* d_in, const int* in_sizes, int n_in,
                              void* d_out, int out_size, void* d_ws, size_t ws_size,
                              hipStream_t stream) {
  (void)in_sizes; (void)n_in; (void)out_size; (void)ws_size;
  const float* adj  = (const float*)d_in[0];
  const float* x    = (const float*)d_in[1];
  const float* cWs0 = (const float*)d_in[2];
  const float* cbs0 = (const float*)d_in[3];
  const float* cWe0 = (const float*)d_in[4];
  const float* cbe0 = (const float*)d_in[5];
  const float* cg0  = (const float*)d_in[6];
  const float* cb0  = (const float*)d_in[7];
  const float* cWs1 = (const float*)d_in[8];
  const float* cbs1 = (const float*)d_in[9];
  const float* cWe1 = (const float*)d_in[10];
  const float* cbe1 = (const float*)d_in[11];
  const float* cg1  = (const float*)d_in[12];
  const float* cb1  = (const float*)d_in[13];
  const float* lW0  = (const float*)d_in[14];
  const float* lb0  = (const float*)d_in[15];
  const float* lg0  = (const float*)d_in[16];
  const float* lbb0 = (const float*)d_in[17];
  const float* fW   = (const float*)d_in[18];
  const float* fb   = (const float*)d_in[19];
  float* out = (float*)d_out;

  // ---- workspace layout ----
  char* p = (char*)d_ws;
  float* stats = (float*)p;                     p += 1024;
  unsigned short* Wg0  = (unsigned short*)p;    p += 256 * 96 * 2;
  unsigned short* Wfb  = (unsigned short*)p;    p += 32 * 512 * 2;
  unsigned short* Wbig = (unsigned short*)p;    p += 1280 * 256 * 2;
  unsigned short* Wl   = (unsigned short*)p;    p += 512 * 256 * 2;
  float* part0 = (float*)p;                     p += 2048 * 76 * 4;
  float* part1 = (float*)p;                     p += 2048 * 76 * 4;
  float* part2 = (float*)p;                     p += 1216 * 76 * 4;
  unsigned short* g0   = (unsigned short*)p;    p += (size_t)M_ * 256 * 2;
  unsigned short* h2   = (unsigned short*)p;    p += (size_t)M_ * 256 * 2;
  unsigned short* big  = (unsigned short*)p;    // Y-half (99.6MB) then g2 (79.7MB)
  unsigned short* Ybuf = big;
  unsigned short* g2   = big;

  float* st0 = stats;
  float* st1 = stats + 76;
  float* st2 = stats + 152;

  k_build_wg0<<<96, 256, 0, stream>>>(cWs0, cbs0, cWe0, cbe0, Wg0);
  k_build_wbig<<<1280, 256, 0, stream>>>(cWs1, cWe1, Wbig);
  k_build_wl<<<512, 256, 0, stream>>>(lW0, Wl);
  k_build_wf<<<64, 256, 0, stream>>>(fW, Wfb);

  // layer 0 (full MFMA; writes g0 raw + stats partials)
  k_gconv0<<<2048, 256, 0, stream>>>(adj, x, Wg0, g0, part0);
  k_gred<<<76, 256, 0, stream>>>(part0, 2048, st0);

  // layer 1: Y = BN0ReLU(g0) * Wbig^T, then per-b adj contraction; 2 halves
  for (int hh = 0; hh < 2; ++hh) {
    k_gemm<false, false><<<dim3(304, 5), 512, 0, stream>>>(
        g0 + (size_t)hh * (M_ / 2) * 256, Wbig, (const float*)nullptr,
        st0, cg0, cb0, 2048.f * 256.f, Ybuf, 1280, (float*)nullptr);
    k_hr<<<1024, 256, 0, stream>>>(adj, Ybuf, cbs1, cbe1, h2, hh * 1024, part1);
  }
  k_gred<<<76, 256, 0, stream>>>(part1, 2048, st1);

  // layer 2: g2 = BN1ReLU(h2) * Wl^T + lb0  (+ stats partials)
  k_gemm<true, true><<<dim3(608, 2), 512, 0, stream>>>(
      h2, Wl, lb0, st1, cg1, cb1, 2048.f * 256.f, g2, 512, part2);
  k_gred<<<76, 256, 0, stream>>>(part2, 1216, st2);

  // final
  k_final<<<2048, 256, 0, stream>>>(g2, x, Wfb, fb, st2, lg0, lbb0, out);
}